// Round 2
// baseline (1099.316 us; speedup 1.0000x reference)
//
#include <hip/hip_runtime.h>

// FSAS slab pipeline: x(4,64,256,256)
//   k2: affine(kv) + 1x1 conv 64->384 into hid slab (34 rows incl. 1-row halo)
//   k3: grouped 3x3 (192 groups of 2 in-ch) -> qkv slab (32 rows)
//   kC: per-8x8-patch circular conv(q,k) + LN(128) + *v + 1x1 128->64 -> out
// Workspace (floats):
//   kv  @ 0       (512)
//   whT @ 512     (24576)  whT[c*384+o] = w_hidden[o][c]
//   wpT @ 25088   (8192)   wpT[c*64+o]  = w_proj[o][c]
//   hid @ 40960   [4][384][34][256]  = 13,369,344 floats (53.5 MB)
//   qkv @ 13410304 [4][384][32][256] = 12,582,912 floats (50.3 MB)
// Total ws: 25,993,216 floats ~= 104 MB.

#define HW    65536
#define SLAB  32
#define HROWS 34          // SLAB + 2 halo rows
#define HSZ   (HROWS*256) // 8704 floats per (b,ch) hid plane
#define QSZ   (SLAB*256)  // 8192 floats per (b,ch) qkv plane

__global__ void k_prep(const float* __restrict__ prior, const float* __restrict__ wk,
                       const float* __restrict__ wh, const float* __restrict__ wp,
                       float* __restrict__ kv, float* __restrict__ whT, float* __restrict__ wpT) {
    int t = blockIdx.x * 256 + threadIdx.x;
    if (t < 512) {
        int b = t >> 7, k = t & 127;
        const float* p = prior + b * 192;
        const float* w = wk + k * 192;
        float s = 0.f;
        for (int f = 0; f < 192; ++f) s = fmaf(p[f], w[f], s);
        kv[t] = s;
        return;
    }
    t -= 512;
    if (t < 24576) {                 // whT[c*384+o] = wh[o*64+c]
        int c = t / 384, o = t - c * 384;
        whT[t] = wh[o * 64 + c];
        return;
    }
    t -= 24576;                      // t < 8192 : wpT[c*64+o] = wp[o*128+c]
    int c = t >> 6, o = t & 63;
    wpT[t] = wp[o * 128 + c];
}

// hid[b][ch][row][col] for slab rows r0-1 .. r0+32 (34 rows); zero-pad OOB rows.
// One block = one hid row x 64 output channels. Thread = one column.
__global__ __launch_bounds__(256) void k2_hidden(const float* __restrict__ x,
    const float* __restrict__ whT, const float* __restrict__ kv,
    float* __restrict__ hid, int r0) {
    int row = blockIdx.x;            // 0..33
    int col = threadIdx.x;
    int chunk = blockIdx.y;          // 0..5 (64 out-ch each)
    int b = blockIdx.z;
    int g = r0 - 1 + row;            // global image row
    float* hb = hid + ((size_t)(b * 384 + chunk * 64)) * HSZ + row * 256 + col;
    if (g < 0 || g > 255) {
        #pragma unroll
        for (int j = 0; j < 64; ++j) hb[(size_t)j * HSZ] = 0.f;
        return;
    }
    const float* xb = x + (size_t)b * 64 * HW + g * 256 + col;
    const float* kv1 = kv + b * 128;
    const float* kv2 = kv1 + 64;
    float acc[64];
    #pragma unroll
    for (int j = 0; j < 64; ++j) acc[j] = 0.f;
    #pragma unroll 4
    for (int c = 0; c < 64; ++c) {
        float xp = fmaf(xb[(size_t)c * HW], kv1[c], kv2[c]);
        const float* wr = whT + c * 384 + chunk * 64;   // wave-uniform -> scalar loads
        #pragma unroll
        for (int j = 0; j < 64; ++j) acc[j] = fmaf(wr[j], xp, acc[j]);
    }
    #pragma unroll
    for (int j = 0; j < 64; ++j) hb[(size_t)j * HSZ] = acc[j];
}

// grouped 3x3 conv (SAME). Tile 64x16 out pixels; group gl uses hid ch 2gl,2gl+1,
// producing qkv ch 2gl,2gl+1 on slab rows 0..31.
__global__ __launch_bounds__(256) void k3_dw(const float* __restrict__ hid,
    const float* __restrict__ wdw, float* __restrict__ qkv) {
    __shared__ float sIn[2 * 18 * 66];
    int t = threadIdx.x;
    int bid = blockIdx.x;            // 8 tiles: tx 0..3 (x64), ty 0..1 (x16 rows)
    int gl = blockIdx.y;             // 0..191
    int b = blockIdx.z;
    int tx = bid & 3, ty = bid >> 2;
    int x0 = tx * 64, y0 = ty * 16;  // slab-local out rows y0..y0+15
    const float* hbase = hid + ((size_t)(b * 384 + 2 * gl)) * HSZ;
    for (int idx = t; idx < 2 * 18 * 66; idx += 256) {
        int chl = idx >= 1188;
        int rem = idx - chl * 1188;
        int row = rem / 66;          // 0..17 -> hid row y0+row
        int col = rem - row * 66;    // 0..65 -> global col x0+col-1
        int gx = x0 + col - 1;
        float v = 0.f;
        if (gx >= 0 && gx < 256)
            v = hbase[(size_t)chl * HSZ + (y0 + row) * 256 + gx];
        sIn[idx] = v;
    }
    __syncthreads();
    int og = 2 * gl;
    float w0[18], w1[18];
    #pragma unroll
    for (int i = 0; i < 18; ++i) {
        w0[i] = wdw[(size_t)og * 18 + i];
        w1[i] = wdw[(size_t)(og + 1) * 18 + i];
    }
    float* q0 = qkv + ((size_t)(b * 384 + og)) * QSZ;
    for (int pp = 0; pp < 4; ++pp) {
        int pixl = t + 256 * pp;
        int ly = pixl >> 6, lx = pixl & 63;
        float a0 = 0.f, a1 = 0.f;
        #pragma unroll
        for (int i = 0; i < 2; ++i)
            #pragma unroll
            for (int ky = 0; ky < 3; ++ky)
                #pragma unroll
                for (int kx = 0; kx < 3; ++kx) {
                    float v = sIn[i * 1188 + (ly + ky) * 66 + (lx + kx)];
                    a0 = fmaf(w0[i * 9 + ky * 3 + kx], v, a0);
                    a1 = fmaf(w1[i * 9 + ky * 3 + kx], v, a1);
                }
        size_t off = (size_t)(y0 + ly) * 256 + (x0 + lx);
        q0[off] = a0;
        q0[QSZ + off] = a1;
    }
}

// Fused: per 8x8 patch (all 128 channels): circular conv(q,k) -> LN over ch ->
// * v -> proj 128->64 -> out. One block per patch.
__global__ __launch_bounds__(256) void kC_patch(const float* __restrict__ qkv,
    const float* __restrict__ wpT, const float* __restrict__ lnw,
    const float* __restrict__ lnb, float* __restrict__ outp, int r0) {
    __shared__ float sA[128 * 72];   // phase1: q [c][pix] stride 72; phase2: conv [pix][c] stride 129
    __shared__ float sB[128 * 72];   // phase1: k [c][pix] stride 72; phase2: v    [pix][c] stride 129
    __shared__ float sPart[4 * 64], sPart2[4 * 64], sMu[64], sRstd[64];
    int t = threadIdx.x;
    int pid = blockIdx.x;            // 0..127 : pyb 0..3 (slab patch-row), pxb 0..31
    int b = blockIdx.y;
    int pyb = pid >> 5, pxb = pid & 31;

    // stage q,k (float4 x2 per (ch,row))
    #pragma unroll
    for (int j = 0; j < 4; ++j) {
        int p = t + 256 * j;         // 0..1023
        int ch = p >> 3, r = p & 7;
        size_t go = ((size_t)(b * 384 + ch)) * QSZ + (pyb * 8 + r) * 256 + pxb * 8;
        const float4* gq = (const float4*)(qkv + go);
        const float4* gk = (const float4*)(qkv + go + (size_t)128 * QSZ);
        float4 q0 = gq[0], q1 = gq[1];
        float4 k0 = gk[0], k1 = gk[1];
        float4* dq = (float4*)(sA + ch * 72 + r * 8);
        float4* dk = (float4*)(sB + ch * 72 + r * 8);
        dq[0] = q0; dq[1] = q1;
        dk[0] = k0; dk[1] = k1;
    }
    __syncthreads();

    // circular conv: task (c,py) -> out row py of channel c
    float conv[4][8];
    #pragma unroll
    for (int it = 0; it < 4; ++it) {
        int task = t + 256 * it;     // 0..1023
        int c = task >> 3, py = task & 7;
        float acc[8];
        #pragma unroll
        for (int px = 0; px < 8; ++px) acc[px] = 0.f;
        #pragma unroll
        for (int iy = 0; iy < 8; ++iy) {
            int krow = (py - iy) & 7;
            float qr[8], kr[8];
            #pragma unroll
            for (int ix = 0; ix < 8; ++ix) qr[ix] = sA[c * 72 + iy * 8 + ix];
            #pragma unroll
            for (int ix = 0; ix < 8; ++ix) kr[ix] = sB[c * 72 + krow * 8 + ix];
            #pragma unroll
            for (int ix = 0; ix < 8; ++ix)
                #pragma unroll
                for (int px = 0; px < 8; ++px)
                    acc[px] = fmaf(qr[ix], kr[(px - ix) & 7], acc[px]);
        }
        #pragma unroll
        for (int px = 0; px < 8; ++px) conv[it][px] = acc[px];
    }
    __syncthreads();

    // re-lay conv as [pix][c] stride 129 (odd stride -> <=2-way bank alias, free)
    #pragma unroll
    for (int it = 0; it < 4; ++it) {
        int task = t + 256 * it;
        int c = task >> 3, py = task & 7;
        #pragma unroll
        for (int px = 0; px < 8; ++px) sA[(py * 8 + px) * 129 + c] = conv[it][px];
    }
    // stage v as [pix][c] stride 129
    #pragma unroll
    for (int j = 0; j < 4; ++j) {
        int p = t + 256 * j;
        int ch = p >> 3, r = p & 7;
        size_t go = ((size_t)(b * 384 + 256 + ch)) * QSZ + (pyb * 8 + r) * 256 + pxb * 8;
        const float4* gv = (const float4*)(qkv + go);
        float4 v0 = gv[0], v1 = gv[1];
        sB[(r * 8 + 0) * 129 + ch] = v0.x;
        sB[(r * 8 + 1) * 129 + ch] = v0.y;
        sB[(r * 8 + 2) * 129 + ch] = v0.z;
        sB[(r * 8 + 3) * 129 + ch] = v0.w;
        sB[(r * 8 + 4) * 129 + ch] = v1.x;
        sB[(r * 8 + 5) * 129 + ch] = v1.y;
        sB[(r * 8 + 6) * 129 + ch] = v1.z;
        sB[(r * 8 + 7) * 129 + ch] = v1.w;
    }
    __syncthreads();

    // LN stats: 4-way partial sums over channels per pixel
    {
        int px = t & 63, qtr = t >> 6;
        float s = 0.f, s2 = 0.f;
        for (int c = qtr * 32; c < qtr * 32 + 32; ++c) {
            float v = sA[px * 129 + c];
            s += v;
            s2 = fmaf(v, v, s2);
        }
        sPart[qtr * 64 + px] = s;
        sPart2[qtr * 64 + px] = s2;
    }
    __syncthreads();
    if (t < 64) {
        float s  = sPart[t] + sPart[64 + t] + sPart[128 + t] + sPart[192 + t];
        float s2 = sPart2[t] + sPart2[64 + t] + sPart2[128 + t] + sPart2[192 + t];
        float mu = s * (1.f / 128.f);
        float var = s2 * (1.f / 128.f) - mu * mu;
        sMu[t] = mu;
        sRstd[t] = rsqrtf(var + 1e-5f);
    }
    __syncthreads();

    // normalize, *v, proj 128->64 (wpT read at wave-uniform addr -> scalar loads)
    {
        int px = t & 63, og = (t >> 6) * 16;
        float mu = sMu[px], rstd = sRstd[px];
        float acc[16];
        #pragma unroll
        for (int j = 0; j < 16; ++j) acc[j] = 0.f;
        #pragma unroll 2
        for (int c = 0; c < 128; ++c) {
            float cv = sA[px * 129 + c];
            float vv = sB[px * 129 + c];
            float tv = fmaf((cv - mu) * rstd, lnw[c], lnb[c]) * vv;
            const float* wr = wpT + c * 64 + og;
            #pragma unroll
            for (int j = 0; j < 16; ++j) acc[j] = fmaf(wr[j], tv, acc[j]);
        }
        int grow = r0 + pyb * 8 + (px >> 3);
        int gcol = pxb * 8 + (px & 7);
        float* ob = outp + (size_t)(b * 64 + og) * HW + grow * 256 + gcol;
        #pragma unroll
        for (int j = 0; j < 16; ++j) ob[(size_t)j * HW] = acc[j];
    }
}

extern "C" void kernel_launch(void* const* d_in, const int* in_sizes, int n_in,
                              void* d_out, int out_size, void* d_ws, size_t ws_size,
                              hipStream_t stream) {
    const float* x     = (const float*)d_in[0];
    const float* prior = (const float*)d_in[1];
    const float* wk    = (const float*)d_in[2];
    const float* wh    = (const float*)d_in[3];
    const float* wdw   = (const float*)d_in[4];
    const float* wp    = (const float*)d_in[5];
    const float* lnw   = (const float*)d_in[6];
    const float* lnb   = (const float*)d_in[7];
    float* out = (float*)d_out;
    float* ws  = (float*)d_ws;

    float* kv  = ws;
    float* whT = ws + 512;
    float* wpT = ws + 512 + 24576;
    float* hid = ws + 40960;                       // [4][384][34][256]
    float* qkv = hid + (size_t)4 * 384 * HSZ;      // [4][384][32][256]

    k_prep<<<dim3(130), dim3(256), 0, stream>>>(prior, wk, wh, wp, kv, whT, wpT);
    for (int slab = 0; slab < 8; ++slab) {
        int r0 = slab * SLAB;
        k2_hidden<<<dim3(HROWS, 6, 4), dim3(256), 0, stream>>>(x, whT, kv, hid, r0);
        k3_dw<<<dim3(8, 192, 4), dim3(256), 0, stream>>>(hid, wdw, qkv);
        kC_patch<<<dim3(128, 4), dim3(256), 0, stream>>>(qkv, wpT, lnw, lnb, out, r0);
    }
}

// Round 3
// 1003.294 us; speedup vs baseline: 1.0957x; 1.0957x over previous
//
#include <hip/hip_runtime.h>

// FSAS slab pipeline: x(4,64,256,256)
//   k2: affine(kv) + 1x1 conv 64->384 into hid slab (34 rows incl. halo)
//   k3: grouped 3x3 -> qkv slab in PATCHIFIED layout [ch][patch(128)][64]
//   kC: thread-per-channel circular conv (q,k in VGPRs) + LN + *v + proj -> out
// Workspace (floats):
//   kv  @ 0       (512)
//   whT @ 512     (24576)  whT[c*384+o] = w_hidden[o][c]
//   wpT @ 25088   (8192)   wpT[c*64+o]  = w_proj[o][c]
//   hid @ 40960   [4][384][34][256]  (53.5 MB)
//   qkv @ hid+4*384*HSZ  [4][384][128][64] patchified (50.3 MB)

#define HW    65536
#define SLAB  32
#define HROWS 34
#define HSZ   (HROWS*256)
#define QSZ   (SLAB*256)   // 8192 floats per (b,ch) plane (= 128 patches * 64)

__global__ void k_prep(const float* __restrict__ prior, const float* __restrict__ wk,
                       const float* __restrict__ wh, const float* __restrict__ wp,
                       float* __restrict__ kv, float* __restrict__ whT, float* __restrict__ wpT) {
    int t = blockIdx.x * 256 + threadIdx.x;
    if (t < 512) {
        int b = t >> 7, k = t & 127;
        const float* p = prior + b * 192;
        const float* w = wk + k * 192;
        float s = 0.f;
        for (int f = 0; f < 192; ++f) s = fmaf(p[f], w[f], s);
        kv[t] = s;
        return;
    }
    t -= 512;
    if (t < 24576) {
        int c = t / 384, o = t - c * 384;
        whT[t] = wh[o * 64 + c];
        return;
    }
    t -= 24576;
    int c = t >> 6, o = t & 63;
    wpT[t] = wp[o * 128 + c];
}

__global__ __launch_bounds__(256) void k2_hidden(const float* __restrict__ x,
    const float* __restrict__ whT, const float* __restrict__ kv,
    float* __restrict__ hid, int r0) {
    int row = blockIdx.x;            // 0..33
    int col = threadIdx.x;
    int chunk = blockIdx.y;          // 0..5
    int b = blockIdx.z;
    int g = r0 - 1 + row;
    float* hb = hid + ((size_t)(b * 384 + chunk * 64)) * HSZ + row * 256 + col;
    if (g < 0 || g > 255) {
        #pragma unroll
        for (int j = 0; j < 64; ++j) hb[(size_t)j * HSZ] = 0.f;
        return;
    }
    const float* xb = x + (size_t)b * 64 * HW + g * 256 + col;
    const float* kv1 = kv + b * 128;
    const float* kv2 = kv1 + 64;
    float acc[64];
    #pragma unroll
    for (int j = 0; j < 64; ++j) acc[j] = 0.f;
    #pragma unroll 4
    for (int c = 0; c < 64; ++c) {
        float xp = fmaf(xb[(size_t)c * HW], kv1[c], kv2[c]);
        const float* wr = whT + c * 384 + chunk * 64;   // wave-uniform -> scalar loads
        #pragma unroll
        for (int j = 0; j < 64; ++j) acc[j] = fmaf(wr[j], xp, acc[j]);
    }
    #pragma unroll
    for (int j = 0; j < 64; ++j) hb[(size_t)j * HSZ] = acc[j];
}

// grouped 3x3 conv; writes qkv in patchified layout [ch][patch][py*8+px]
__global__ __launch_bounds__(256) void k3_dw(const float* __restrict__ hid,
    const float* __restrict__ wdw, float* __restrict__ qkv) {
    __shared__ float sIn[2 * 18 * 66];
    int t = threadIdx.x;
    int bid = blockIdx.x;            // tx 0..3 (x64), ty 0..1 (x16 rows)
    int gl = blockIdx.y;             // 0..191
    int b = blockIdx.z;
    int tx = bid & 3, ty = bid >> 2;
    int x0 = tx * 64, y0 = ty * 16;
    const float* hbase = hid + ((size_t)(b * 384 + 2 * gl)) * HSZ;
    for (int idx = t; idx < 2 * 18 * 66; idx += 256) {
        int chl = idx >= 1188;
        int rem = idx - chl * 1188;
        int row = rem / 66;
        int col = rem - row * 66;
        int gx = x0 + col - 1;
        float v = 0.f;
        if (gx >= 0 && gx < 256)
            v = hbase[(size_t)chl * HSZ + (y0 + row) * 256 + gx];
        sIn[idx] = v;
    }
    __syncthreads();
    int og = 2 * gl;
    float w0[18], w1[18];
    #pragma unroll
    for (int i = 0; i < 18; ++i) {
        w0[i] = wdw[(size_t)og * 18 + i];
        w1[i] = wdw[(size_t)(og + 1) * 18 + i];
    }
    float* q0 = qkv + ((size_t)(b * 384 + og)) * QSZ;
    for (int pp = 0; pp < 4; ++pp) {
        int pixl = t + 256 * pp;
        int ly = pixl >> 6, lx = pixl & 63;
        float a0 = 0.f, a1 = 0.f;
        #pragma unroll
        for (int i = 0; i < 2; ++i)
            #pragma unroll
            for (int ky = 0; ky < 3; ++ky)
                #pragma unroll
                for (int kx = 0; kx < 3; ++kx) {
                    float v = sIn[i * 1188 + (ly + ky) * 66 + (lx + kx)];
                    a0 = fmaf(w0[i * 9 + ky * 3 + kx], v, a0);
                    a1 = fmaf(w1[i * 9 + ky * 3 + kx], v, a1);
                }
        int row = y0 + ly;                                  // slab row 0..31
        int gx = x0 + lx;
        int patch = (row >> 3) * 32 + (gx >> 3);            // 0..127
        int off = patch * 64 + (row & 7) * 8 + (gx & 7);
        q0[off] = a0;
        q0[QSZ + off] = a1;
    }
}

// Fused per-patch: circular conv (q,k in regs) + LN(128) + *v + proj 128->64.
// Thread t: channel c = t&127, py-half pyh = t>>7 (rows pyh*4..pyh*4+3).
__global__ __launch_bounds__(256, 2) void kC_patch(const float* __restrict__ qkv,
    const float* __restrict__ wpT, const float* __restrict__ lnw,
    const float* __restrict__ lnb, float* __restrict__ outp, int r0) {
    __shared__ float sConv[64 * 129];            // [pix][c], 2-way max bank alias
    __shared__ float sRedS[256], sRedQ[256];
    __shared__ float sMu[64], sRstd[64];
    int t = threadIdx.x;
    int p = blockIdx.x;              // slab-local patch 0..127
    int b = blockIdx.y;
    int c = t & 127;
    int pyh = t >> 7;

    const float4* gq = (const float4*)(qkv + ((size_t)(b * 384 + c)) * QSZ + p * 64);
    const float4* gk = (const float4*)(qkv + ((size_t)(b * 384 + 128 + c)) * QSZ + p * 64);
    float q[64], k[64];
    #pragma unroll
    for (int f = 0; f < 16; ++f) {
        float4 v4 = gq[f];
        q[f * 4 + 0] = v4.x; q[f * 4 + 1] = v4.y;
        q[f * 4 + 2] = v4.z; q[f * 4 + 3] = v4.w;
    }
    // k rows pre-rotated: reg row s = global row (s + 4*pyh)&7  -> all conv
    // register indices become compile-time constants.
    #pragma unroll
    for (int s = 0; s < 8; ++s) {
        int r = (s + 4 * pyh) & 7;
        float4 v0 = gk[r * 2], v1 = gk[r * 2 + 1];
        k[s * 8 + 0] = v0.x; k[s * 8 + 1] = v0.y; k[s * 8 + 2] = v0.z; k[s * 8 + 3] = v0.w;
        k[s * 8 + 4] = v1.x; k[s * 8 + 5] = v1.y; k[s * 8 + 6] = v1.z; k[s * 8 + 7] = v1.w;
    }
    float acc[4][8];
    #pragma unroll
    for (int it = 0; it < 4; ++it)
        #pragma unroll
        for (int px = 0; px < 8; ++px) acc[it][px] = 0.f;
    #pragma unroll
    for (int iy = 0; iy < 8; ++iy)
        #pragma unroll
        for (int ix = 0; ix < 8; ++ix) {
            float qv = q[iy * 8 + ix];
            #pragma unroll
            for (int it = 0; it < 4; ++it) {
                int ks = (it - iy) & 7;          // compile-time
                #pragma unroll
                for (int px = 0; px < 8; ++px)
                    acc[it][px] = fmaf(qv, k[ks * 8 + ((px - ix) & 7)], acc[it][px]);
            }
        }
    // conv -> LDS [pix][c]
    #pragma unroll
    for (int it = 0; it < 4; ++it) {
        int pix0 = (pyh * 4 + it) * 8;
        #pragma unroll
        for (int px = 0; px < 8; ++px)
            sConv[(pix0 + px) * 129 + c] = acc[it][px];
    }
    // prefetch v for this thread's 32 pixels (latency hidden under stats phase)
    const float4* gv = (const float4*)(qkv + ((size_t)(b * 384 + 256 + c)) * QSZ
                                       + p * 64 + pyh * 32);
    float vv[32];
    #pragma unroll
    for (int f = 0; f < 8; ++f) {
        float4 v4 = gv[f];
        vv[f * 4 + 0] = v4.x; vv[f * 4 + 1] = v4.y;
        vv[f * 4 + 2] = v4.z; vv[f * 4 + 3] = v4.w;
    }
    float lw = lnw[c], lb = lnb[c];
    __syncthreads();

    // LN stats: thread (px, quarter) sums 32 channels
    {
        int px = t & 63, q4 = t >> 6;
        float s = 0.f, s2 = 0.f;
        #pragma unroll
        for (int j = 0; j < 32; ++j) {
            float v = sConv[px * 129 + q4 * 32 + j];
            s += v;
            s2 = fmaf(v, v, s2);
        }
        sRedS[q4 * 64 + px] = s;
        sRedQ[q4 * 64 + px] = s2;
    }
    __syncthreads();
    if (t < 64) {
        float s  = sRedS[t] + sRedS[64 + t] + sRedS[128 + t] + sRedS[192 + t];
        float s2 = sRedQ[t] + sRedQ[64 + t] + sRedQ[128 + t] + sRedQ[192 + t];
        float mu = s * (1.f / 128.f);
        float var = s2 * (1.f / 128.f) - mu * mu;
        sMu[t] = mu;
        sRstd[t] = rsqrtf(var + 1e-5f);
    }
    __syncthreads();
    // tv = (norm(conv)*lnw+lnb) * v  -> back into sConv
    #pragma unroll
    for (int it = 0; it < 4; ++it) {
        #pragma unroll
        for (int px = 0; px < 8; ++px) {
            int pix = (pyh * 4 + it) * 8 + px;
            float tvv = fmaf((acc[it][px] - sMu[pix]) * sRstd[pix], lw, lb)
                        * vv[it * 8 + px];
            sConv[pix * 129 + c] = tvv;
        }
    }
    __syncthreads();
    // proj 128->64: thread (px, og-group of 16), wpT at wave-uniform addr
    {
        int px = t & 63, og = (t >> 6) * 16;
        float po[16];
        #pragma unroll
        for (int j = 0; j < 16; ++j) po[j] = 0.f;
        #pragma unroll 2
        for (int cc = 0; cc < 128; ++cc) {
            float tvv = sConv[px * 129 + cc];
            const float* wr = wpT + cc * 64 + og;
            #pragma unroll
            for (int j = 0; j < 16; ++j) po[j] = fmaf(wr[j], tvv, po[j]);
        }
        int grow = r0 + (p >> 5) * 8 + (px >> 3);
        int gcol = (p & 31) * 8 + (px & 7);
        float* ob = outp + ((size_t)(b * 64 + og)) * HW + grow * 256 + gcol;
        #pragma unroll
        for (int j = 0; j < 16; ++j) ob[(size_t)j * HW] = po[j];
    }
}

extern "C" void kernel_launch(void* const* d_in, const int* in_sizes, int n_in,
                              void* d_out, int out_size, void* d_ws, size_t ws_size,
                              hipStream_t stream) {
    const float* x     = (const float*)d_in[0];
    const float* prior = (const float*)d_in[1];
    const float* wk    = (const float*)d_in[2];
    const float* wh    = (const float*)d_in[3];
    const float* wdw   = (const float*)d_in[4];
    const float* wp    = (const float*)d_in[5];
    const float* lnw   = (const float*)d_in[6];
    const float* lnb   = (const float*)d_in[7];
    float* out = (float*)d_out;
    float* ws  = (float*)d_ws;

    float* kv  = ws;
    float* whT = ws + 512;
    float* wpT = ws + 512 + 24576;
    float* hid = ws + 40960;
    float* qkv = hid + (size_t)4 * 384 * HSZ;

    k_prep<<<dim3(130), dim3(256), 0, stream>>>(prior, wk, wh, wp, kv, whT, wpT);
    for (int slab = 0; slab < 8; ++slab) {
        int r0 = slab * SLAB;
        k2_hidden<<<dim3(HROWS, 6, 4), dim3(256), 0, stream>>>(x, whT, kv, hid, r0);
        k3_dw<<<dim3(8, 192, 4), dim3(256), 0, stream>>>(hid, wdw, qkv);
        kC_patch<<<dim3(128, 4), dim3(256), 0, stream>>>(qkv, wpT, lnw, lnb, out, r0);
    }
}

// Round 4
// 987.980 us; speedup vs baseline: 1.1127x; 1.0155x over previous
//
#include <hip/hip_runtime.h>

// FSAS slab pipeline, 4 slabs of 64 rows, bf16 intermediates:
//   k2: affine(kv) + 1x1 conv 64->384 -> hid bf16 slab (66 rows incl. halo)
//   k3: grouped 3x3 -> qkv bf16 slab, PATCHIFIED [ch][patch(256)][64]
//   kC: per-patch circular conv (q,k in VGPRs) + LN + *v + proj 128->64 -> out
// Workspace:
//   kv  fp32 @ 0      (512)
//   whT fp32 @ 512    (24576)  whT[c*384+o] = w_hidden[o][c]
//   wpT fp32 @ 25088  (8192)   wpT[c*64+o]  = w_proj[o][c]
//   hid bf16 @ float-ofs 40960 : [4][384][66][256]  (51.9 MB)
//   qkv bf16 after hid          : [4][384][256][64]  (50.3 MB)
// Total 102,400,000 B = 97.66 MiB (< proven 99.15 MiB).

#define HW    65536
#define SLAB  64
#define HROWS 66
#define HSZ2  (HROWS*256)   // bf16 elems per (b,ch) hid plane
#define QS    16384         // bf16 elems per (b,ch) qkv plane (256 patches * 64)

__device__ __forceinline__ unsigned short f2bf(float f) {
    unsigned u = __float_as_uint(f);
    u += 0x7FFFu + ((u >> 16) & 1u);       // RNE
    return (unsigned short)(u >> 16);
}
__device__ __forceinline__ float bflo(unsigned u) { return __uint_as_float(u << 16); }
__device__ __forceinline__ float bfhi(unsigned u) { return __uint_as_float(u & 0xFFFF0000u); }

__global__ void k_prep(const float* __restrict__ prior, const float* __restrict__ wk,
                       const float* __restrict__ wh, const float* __restrict__ wp,
                       float* __restrict__ kv, float* __restrict__ whT, float* __restrict__ wpT) {
    int t = blockIdx.x * 256 + threadIdx.x;
    if (t < 512) {
        int b = t >> 7, k = t & 127;
        const float* p = prior + b * 192;
        const float* w = wk + k * 192;
        float s = 0.f;
        for (int f = 0; f < 192; ++f) s = fmaf(p[f], w[f], s);
        kv[t] = s;
        return;
    }
    t -= 512;
    if (t < 24576) {
        int c = t / 384, o = t - c * 384;
        whT[t] = wh[o * 64 + c];
        return;
    }
    t -= 24576;
    int c = t >> 6, o = t & 63;
    wpT[t] = wp[o * 128 + c];
}

// Thread: row-sub (t>>7) of a row-pair block, col pair 2*(t&127). 64 out-ch chunk.
__global__ __launch_bounds__(256, 2) void k2_hidden(const float* __restrict__ x,
    const float* __restrict__ whT, const float* __restrict__ kv,
    unsigned short* __restrict__ hid, int r0) {
    int row = blockIdx.x * 2 + (threadIdx.x >> 7);   // 0..65
    int cp = threadIdx.x & 127;
    int chunk = blockIdx.y;          // 0..5
    int b = blockIdx.z;
    int g = r0 - 1 + row;
    unsigned* hb = (unsigned*)(hid + ((size_t)(b * 384 + chunk * 64)) * HSZ2
                               + row * 256 + cp * 2);
    if (g < 0 || g > 255) {
        #pragma unroll
        for (int j = 0; j < 64; ++j) hb[(size_t)j * (HSZ2 / 2)] = 0u;
        return;
    }
    const float2* xb = (const float2*)(x + (size_t)b * 64 * HW + g * 256 + cp * 2);
    const float* kv1 = kv + b * 128;
    const float* kv2 = kv1 + 64;
    float acc0[64], acc1[64];
    #pragma unroll
    for (int j = 0; j < 64; ++j) { acc0[j] = 0.f; acc1[j] = 0.f; }
    #pragma unroll 4
    for (int c = 0; c < 64; ++c) {
        float2 xv = xb[(size_t)c * (HW / 2)];
        float xp0 = fmaf(xv.x, kv1[c], kv2[c]);
        float xp1 = fmaf(xv.y, kv1[c], kv2[c]);
        const float* wr = whT + c * 384 + chunk * 64;   // wave-uniform -> scalar loads
        #pragma unroll
        for (int j = 0; j < 64; ++j) {
            acc0[j] = fmaf(wr[j], xp0, acc0[j]);
            acc1[j] = fmaf(wr[j], xp1, acc1[j]);
        }
    }
    #pragma unroll
    for (int j = 0; j < 64; ++j)
        hb[(size_t)j * (HSZ2 / 2)] = (unsigned)f2bf(acc0[j]) | ((unsigned)f2bf(acc1[j]) << 16);
}

// grouped 3x3 conv from bf16 hid -> bf16 qkv patchified [ch][patch][py*8+px]
__global__ __launch_bounds__(256) void k3_dw(const unsigned short* __restrict__ hid,
    const float* __restrict__ wdw, unsigned short* __restrict__ qkv) {
    __shared__ float sIn[2 * 18 * 66];
    int t = threadIdx.x;
    int bid = blockIdx.x;            // 16 tiles: tx 0..3 (x64 cols), ty 0..3 (x16 rows)
    int gl = blockIdx.y;             // 0..191
    int b = blockIdx.z;
    int tx = bid & 3, ty = bid >> 2;
    int x0 = tx * 64, y0 = ty * 16;
    const unsigned short* hbase = hid + ((size_t)(b * 384 + 2 * gl)) * HSZ2;
    for (int idx = t; idx < 2 * 18 * 66; idx += 256) {
        int chl = idx >= 1188;
        int rem = idx - chl * 1188;
        int row = rem / 66;
        int col = rem - row * 66;
        int gx = x0 + col - 1;
        float v = 0.f;
        if (gx >= 0 && gx < 256)
            v = bflo((unsigned)hbase[(size_t)chl * HSZ2 + (y0 + row) * 256 + gx]);
        sIn[idx] = v;
    }
    __syncthreads();
    int og = 2 * gl;
    float w0[18], w1[18];
    #pragma unroll
    for (int i = 0; i < 18; ++i) {
        w0[i] = wdw[(size_t)og * 18 + i];
        w1[i] = wdw[(size_t)(og + 1) * 18 + i];
    }
    unsigned short* q0 = qkv + ((size_t)(b * 384 + og)) * QS;
    #pragma unroll
    for (int pp = 0; pp < 2; ++pp) {
        int ly = pp * 8 + (t >> 5);                  // 0..15
        int lxp = (t & 31) * 2;                      // even col in tile
        float a[2][2];                               // [px][out-ch]
        #pragma unroll
        for (int px = 0; px < 2; ++px) {
            float s0 = 0.f, s1 = 0.f;
            #pragma unroll
            for (int i = 0; i < 2; ++i)
                #pragma unroll
                for (int ky = 0; ky < 3; ++ky)
                    #pragma unroll
                    for (int kx = 0; kx < 3; ++kx) {
                        float v = sIn[i * 1188 + (ly + ky) * 66 + (lxp + px + kx)];
                        s0 = fmaf(w0[i * 9 + ky * 3 + kx], v, s0);
                        s1 = fmaf(w1[i * 9 + ky * 3 + kx], v, s1);
                    }
            a[px][0] = s0; a[px][1] = s1;
        }
        int row = y0 + ly;                           // slab row 0..63
        int gx = x0 + lxp;
        int patch = (row >> 3) * 32 + (gx >> 3);     // 0..255
        int off = patch * 64 + (row & 7) * 8 + (gx & 7);   // even
        ((unsigned*)(q0 + off))[0] =
            (unsigned)f2bf(a[0][0]) | ((unsigned)f2bf(a[1][0]) << 16);
        ((unsigned*)(q0 + QS + off))[0] =
            (unsigned)f2bf(a[0][1]) | ((unsigned)f2bf(a[1][1]) << 16);
    }
}

// Fused per-patch: circular conv (q,k in regs) + LN(128) + *v + proj 128->64.
// Thread t: channel c = t&127, py-half pyh = t>>7.
__global__ __launch_bounds__(256, 2) void kC_patch(const unsigned short* __restrict__ qkv,
    const float* __restrict__ wpT, const float* __restrict__ lnw,
    const float* __restrict__ lnb, float* __restrict__ outp, int r0) {
    __shared__ float sConv[64 * 129];
    __shared__ float sRedS[256], sRedQ[256];
    __shared__ float sMu[64], sRstd[64];
    int t = threadIdx.x;
    int p = blockIdx.x;              // slab-local patch 0..255
    int b = blockIdx.y;
    int c = t & 127;
    int pyh = t >> 7;

    const uint4* gq = (const uint4*)(qkv + ((size_t)(b * 384 + c)) * QS + p * 64);
    const uint4* gk = (const uint4*)(qkv + ((size_t)(b * 384 + 128 + c)) * QS + p * 64);
    float q[64], k[64];
    #pragma unroll
    for (int f = 0; f < 8; ++f) {                     // 8 bf16 per uint4
        uint4 u = gq[f];
        q[f * 8 + 0] = bflo(u.x); q[f * 8 + 1] = bfhi(u.x);
        q[f * 8 + 2] = bflo(u.y); q[f * 8 + 3] = bfhi(u.y);
        q[f * 8 + 4] = bflo(u.z); q[f * 8 + 5] = bfhi(u.z);
        q[f * 8 + 6] = bflo(u.w); q[f * 8 + 7] = bfhi(u.w);
    }
    // k rows pre-rotated: reg row s = global row (s + 4*pyh)&7 ; one uint4 per row
    #pragma unroll
    for (int s = 0; s < 8; ++s) {
        int r = (s + 4 * pyh) & 7;
        uint4 u = ((const uint4*)gk)[r];
        k[s * 8 + 0] = bflo(u.x); k[s * 8 + 1] = bfhi(u.x);
        k[s * 8 + 2] = bflo(u.y); k[s * 8 + 3] = bfhi(u.y);
        k[s * 8 + 4] = bflo(u.z); k[s * 8 + 5] = bfhi(u.z);
        k[s * 8 + 6] = bflo(u.w); k[s * 8 + 7] = bfhi(u.w);
    }
    float acc[4][8];
    #pragma unroll
    for (int it = 0; it < 4; ++it)
        #pragma unroll
        for (int px = 0; px < 8; ++px) acc[it][px] = 0.f;
    #pragma unroll
    for (int iy = 0; iy < 8; ++iy)
        #pragma unroll
        for (int ix = 0; ix < 8; ++ix) {
            float qv = q[iy * 8 + ix];
            #pragma unroll
            for (int it = 0; it < 4; ++it) {
                int ks = (it - iy) & 7;              // compile-time
                #pragma unroll
                for (int px = 0; px < 8; ++px)
                    acc[it][px] = fmaf(qv, k[ks * 8 + ((px - ix) & 7)], acc[it][px]);
            }
        }
    #pragma unroll
    for (int it = 0; it < 4; ++it) {
        int pix0 = (pyh * 4 + it) * 8;
        #pragma unroll
        for (int px = 0; px < 8; ++px)
            sConv[(pix0 + px) * 129 + c] = acc[it][px];
    }
    // prefetch v (32 bf16 = 4 uint4)
    const uint4* gv = (const uint4*)(qkv + ((size_t)(b * 384 + 256 + c)) * QS
                                     + p * 64 + pyh * 32);
    float vv[32];
    #pragma unroll
    for (int f = 0; f < 4; ++f) {
        uint4 u = gv[f];
        vv[f * 8 + 0] = bflo(u.x); vv[f * 8 + 1] = bfhi(u.x);
        vv[f * 8 + 2] = bflo(u.y); vv[f * 8 + 3] = bfhi(u.y);
        vv[f * 8 + 4] = bflo(u.z); vv[f * 8 + 5] = bfhi(u.z);
        vv[f * 8 + 6] = bflo(u.w); vv[f * 8 + 7] = bfhi(u.w);
    }
    float lw = lnw[c], lb = lnb[c];
    __syncthreads();

    {
        int px = t & 63, q4 = t >> 6;
        float s = 0.f, s2 = 0.f;
        #pragma unroll
        for (int j = 0; j < 32; ++j) {
            float v = sConv[px * 129 + q4 * 32 + j];
            s += v;
            s2 = fmaf(v, v, s2);
        }
        sRedS[q4 * 64 + px] = s;
        sRedQ[q4 * 64 + px] = s2;
    }
    __syncthreads();
    if (t < 64) {
        float s  = sRedS[t] + sRedS[64 + t] + sRedS[128 + t] + sRedS[192 + t];
        float s2 = sRedQ[t] + sRedQ[64 + t] + sRedQ[128 + t] + sRedQ[192 + t];
        float mu = s * (1.f / 128.f);
        float var = s2 * (1.f / 128.f) - mu * mu;
        sMu[t] = mu;
        sRstd[t] = rsqrtf(var + 1e-5f);
    }
    __syncthreads();
    #pragma unroll
    for (int it = 0; it < 4; ++it) {
        #pragma unroll
        for (int px = 0; px < 8; ++px) {
            int pix = (pyh * 4 + it) * 8 + px;
            float tvv = fmaf((acc[it][px] - sMu[pix]) * sRstd[pix], lw, lb)
                        * vv[it * 8 + px];
            sConv[pix * 129 + c] = tvv;
        }
    }
    __syncthreads();
    {
        int px = t & 63, og = (t >> 6) * 16;
        float po[16];
        #pragma unroll
        for (int j = 0; j < 16; ++j) po[j] = 0.f;
        #pragma unroll 2
        for (int cc = 0; cc < 128; ++cc) {
            float tvv = sConv[px * 129 + cc];
            const float* wr = wpT + cc * 64 + og;
            #pragma unroll
            for (int j = 0; j < 16; ++j) po[j] = fmaf(wr[j], tvv, po[j]);
        }
        int grow = r0 + (p >> 5) * 8 + (px >> 3);
        int gcol = (p & 31) * 8 + (px & 7);
        float* ob = outp + ((size_t)(b * 64 + og)) * HW + grow * 256 + gcol;
        #pragma unroll
        for (int j = 0; j < 16; ++j) ob[(size_t)j * HW] = po[j];
    }
}

extern "C" void kernel_launch(void* const* d_in, const int* in_sizes, int n_in,
                              void* d_out, int out_size, void* d_ws, size_t ws_size,
                              hipStream_t stream) {
    const float* x     = (const float*)d_in[0];
    const float* prior = (const float*)d_in[1];
    const float* wk    = (const float*)d_in[2];
    const float* wh    = (const float*)d_in[3];
    const float* wdw   = (const float*)d_in[4];
    const float* wp    = (const float*)d_in[5];
    const float* lnw   = (const float*)d_in[6];
    const float* lnb   = (const float*)d_in[7];
    float* out = (float*)d_out;
    float* ws  = (float*)d_ws;

    float* kv  = ws;
    float* whT = ws + 512;
    float* wpT = ws + 512 + 24576;
    unsigned short* hid = (unsigned short*)(ws + 40960);        // [4][384][66][256] bf16
    unsigned short* qkv = hid + (size_t)4 * 384 * HSZ2;         // [4][384][256][64] bf16

    k_prep<<<dim3(130), dim3(256), 0, stream>>>(prior, wk, wh, wp, kv, whT, wpT);
    for (int slab = 0; slab < 4; ++slab) {
        int r0 = slab * SLAB;
        k2_hidden<<<dim3(HROWS / 2, 6, 4), dim3(256), 0, stream>>>(x, whT, kv, hid, r0);
        k3_dw<<<dim3(16, 192, 4), dim3(256), 0, stream>>>(hid, wdw, qkv);
        kC_patch<<<dim3(256, 4), dim3(256), 0, stream>>>(qkv, wpT, lnw, lnb, out, r0);
    }
}